// Round 1
// baseline (155.782 us; speedup 1.0000x reference)
//
#include <hip/hip_runtime.h>
#include <stdint.h>
#include <math.h>

// RNG (VERIFIED bit-exact, R7/R8/R9 absmax 0.0): jax partitionable threefry,
//   bits[i] = x0 ^ x1 of threefry2x32(key=[0,42], c0=0, c1=i),
//   u = (bits>>9) * 2^-23 exactly, i = ((b*256+s)*4+k).
// Decision: argmax_k [ c_k - log(w_k) ], c_k = mean_k - max(mean),
//   w_k = -log(u_k + 1e-20) + 1e-20 (monotone-equivalent to the reference's
//   argmax(logits+gumbel); first-wins ties = jnp.argmax).
// Algebra (mean=[2,1,1,1] => c1==c2==c3):
//   * within equal-logit group {1,2,3}: ranking == integer argmax of
//     m_k = bits_k>>9 (f64 chain strictly monotone in m; equal m -> equal
//     score -> first-wins).  Zero transcendentals.
//   * group-winner vs class 0:  s0 >= sj  <=>  wm >= K*w0,  K = exp(c1-c0)
//     (wave-uniform).  2 transcendentals/sample total (inside fast_w).
//   * relative margin 4e-6 (error bound ~3e-7) -> exact-f64 fallback keeps
//     decisions bit-exact vs the np reference, incl. true ties.
// Mapping (R9 lesson): one THREAD per sample, one block per row — max TLP
// (65536 short waves) hides cipher/log dep-chains.
// R10 (this round): latency-probe polish —
//   * all 8 candidate loads (4 classes x {A,Bo}) hoisted ABOVE the cipher:
//     they are coalesced (row-contiguous across lanes) and complete under the
//     ~600-cycle threefry chain instead of issuing after it. Same HBM lines
//     as the old per-lane scatter (line granularity already touched ~all 4
//     rows), so traffic is unchanged; only exposed latency is removed.
//   * BEVa/BEVb (block-uniform -> s_load) hoisted from the post-barrier
//     thread-0 tail to kernel top.
//   * fully-inactive waves ((wid<<6) >= kp) skip the 12-level shuffle reduce
//     and just zero their LDS slot.
// Hypothesis test: rocprof shows the timed envelope is dominated by harness
// 268MB re-poison fills at 81-83% HBM peak; bayes_kernel <= 40.3us (absent
// from top-5). If dur_us does not move, the envelope is fill-bound.

__device__ __forceinline__ uint32_t rotl32(uint32_t x, int r) {
    return (x << r) | (x >> (32 - r));   // -> v_alignbit_b32
}

// returns x0 ^ x1 of threefry2x32(key=[0,42], (c0,c1))
__device__ __forceinline__ uint32_t tf2x32_xor(uint32_t c0, uint32_t c1) {
    const uint32_t ks0 = 0u, ks1 = 42u, ks2 = 0x1BD11BF0u; // 0^42^0x1BD11BDA
    uint32_t x0 = c0 + ks0, x1 = c1 + ks1;
#define TF_R(r) { x0 += x1; x1 = rotl32(x1, r); x1 ^= x0; }
    TF_R(13) TF_R(15) TF_R(26) TF_R(6)
    x0 += ks1; x1 += ks2 + 1u;
    TF_R(17) TF_R(29) TF_R(16) TF_R(24)
    x0 += ks2; x1 += ks0 + 2u;
    TF_R(13) TF_R(15) TF_R(26) TF_R(6)
    x0 += ks0; x1 += ks1 + 3u;
    TF_R(17) TF_R(29) TF_R(16) TF_R(24)
    x0 += ks1; x1 += ks2 + 4u;
    TF_R(13) TF_R(15) TF_R(26) TF_R(6)
    x0 += ks2; x1 += ks0 + 5u;
#undef TF_R
    return x0 ^ x1;
}

// fast f32 w = -log(u + 1e-20), relative-accurate everywhere (~3e-7):
// hw log for u <= 0.96875, exact-d series for u -> 1.
__device__ __forceinline__ float fast_w(uint32_t m /* = bits>>9 */) {
    const float u  = (float)m * 0x1p-23f;                    // exact
    const float wl = -__logf(u + 1e-20f);
    const float d  = (float)(0x800000u - m) * 0x1p-23f;      // 1-u exact
    const float d2 = d * d;
    const float ws = d + d2 * (0.5f + d * (0.333333333f + d * (0.25f + d * 0.2f)));
    return (u > 0.96875f) ? ws : wl;
}

// exact f64 log(w) matching the np reference chain (validated bit-exact R8)
__device__ __forceinline__ double exact_lw(uint32_t m) {
    const double u = (double)m * 0x1p-23;
    const double w = -log(u + 1e-20) + 1e-20;
    return log(w);
}

__global__ __launch_bounds__(256) void bayes_kernel(
    const float* __restrict__ A,     // [B,4,S] outcomeA
    const float* __restrict__ Bo,    // [B,4,S] outcomeB
    const float* __restrict__ BEVa,  // [B]
    const float* __restrict__ BEVb,  // [B]
    const int*   __restrict__ kapa,  // [B]
    const float* __restrict__ mean,  // [4]
    float*       __restrict__ out)   // [B]
{
    const int b  = blockIdx.x;          // 0..16383, one block per row
    const int s  = threadIdx.x;         // 0..255, one thread per sample
    const int kp = kapa[b];             // block-uniform
    const float beva = BEVa[b];         // uniform -> SGPR, issued at top
    const float bevb = BEVb[b];

    float av = 0.0f, bv = 0.0f;
    if (s < kp) {                       // masked-out samples never matter
        // ---- candidate loads FIRST: coalesced, in flight under the cipher
        const int base = (b * 4) * 256 + s;
        const float a0 = A[base];
        const float a1 = A[base + 256];
        const float a2 = A[base + 512];
        const float a3 = A[base + 768];
        const float q0 = Bo[base];
        const float q1 = Bo[base + 256];
        const float q2 = Bo[base + 512];
        const float q3 = Bo[base + 768];

        const float m0f = mean[0], m1f = mean[1], m2f = mean[2], m3f = mean[3];
        const float mx = fmaxf(fmaxf(m0f, m1f), fmaxf(m2f, m3f));
        const float c0 = m0f - mx, c1 = m1f - mx, c2 = m2f - mx, c3 = m3f - mx;
        const bool grouped = (c1 == c2) && (c2 == c3);   // uniform branch

        const uint32_t i0 = ((uint32_t)(b * 256 + s)) << 2;
        uint32_t m[4];
#pragma unroll
        for (int k = 0; k < 4; ++k)
            m[k] = tf2x32_xor(0u, i0 + (uint32_t)k) >> 9;

        int ksel = 0;
        if (grouped) {
            // exact integer ranking within equal-logit group {1,2,3}
            int jg = 1; uint32_t mm = m[1];
            if (m[2] > mm) { mm = m[2]; jg = 2; }
            if (m[3] > mm) { mm = m[3]; jg = 3; }
            // class 0 vs group winner:  s0 >= sj  <=>  wm >= K*w0
            const float K  = __expf(c1 - c0);            // uniform
            const float w0 = fast_w(m[0]);
            const float wm = fast_w(mm);
            const float t  = K * w0;
            ksel = (wm >= t) ? 0 : jg;                   // ties -> index 0
            if (fabsf(wm - t) < 4e-6f * (wm + t)) {      // rare exact path
                const double S0 = (double)c0 - exact_lw(m[0]);
                const double Sj = (double)c1 - exact_lw(mm);
                ksel = (S0 >= Sj) ? 0 : jg;
            }
        } else {
            const float cc[4] = { c0, c1, c2, c3 };
            float sc[4];
#pragma unroll
            for (int k = 0; k < 4; ++k)
                sc[k] = cc[k] - __logf(fast_w(m[k]));
            float b1 = sc[0], b2 = -3.4e38f; ksel = 0;
#pragma unroll
            for (int k = 1; k < 4; ++k) {
                if (sc[k] > b1)      { b2 = b1; b1 = sc[k]; ksel = k; }
                else if (sc[k] > b2) { b2 = sc[k]; }
            }
            if (b1 - b2 < 5e-4f) {
                double best = -1.0e308; ksel = 0;
#pragma unroll
                for (int k = 0; k < 4; ++k) {
                    const double sk = (double)cc[k] - exact_lw(m[k]);
                    if (sk > best) { best = sk; ksel = k; }
                }
            }
        }

        // in-register select (3 cndmask per array), same values as the old
        // per-lane gather A[(b*4+ksel)*256+s]
        av = (ksel >= 2) ? ((ksel == 3) ? a3 : a2) : ((ksel == 1) ? a1 : a0);
        bv = (ksel >= 2) ? ((ksel == 3) ? q3 : q2) : ((ksel == 1) ? q1 : q0);
    }

    __shared__ float red[4][2];
    const int wid  = threadIdx.x >> 6;
    const int lane = threadIdx.x & 63;

    if ((wid << 6) < kp) {
        // wave has >=1 active lane: full 64-lane reduce
#pragma unroll
        for (int off = 32; off >= 1; off >>= 1) {
            av += __shfl_down(av, off);
            bv += __shfl_down(bv, off);
        }
        if (lane == 0) { red[wid][0] = av; red[wid][1] = bv; }
    } else if (lane == 0) {
        red[wid][0] = 0.0f; red[wid][1] = 0.0f;
    }
    __syncthreads();

    if (threadIdx.x == 0) {
        float sA = 0.f, sB = 0.f;
#pragma unroll
        for (int w = 0; w < 4; ++w) { sA += red[w][0]; sB += red[w][1]; }
        const double d = (double)kp;
        const double x = (double)bevb - (double)beva
                       + (double)sB / d - (double)sA / d;
        out[b] = (float)(1.0 / (1.0 + exp(-x)));
    }
}

extern "C" void kernel_launch(void* const* d_in, const int* in_sizes, int n_in,
                              void* d_out, int out_size, void* d_ws, size_t ws_size,
                              hipStream_t stream) {
    (void)in_sizes; (void)n_in; (void)d_ws; (void)ws_size; (void)out_size;
    const float* A    = (const float*)d_in[0];  // outcomeA [16384,4,256] f32
    const float* Bo   = (const float*)d_in[1];  // outcomeB [16384,4,256] f32
    const float* BEVa = (const float*)d_in[2];  // [16384] f32
    const float* BEVb = (const float*)d_in[3];  // [16384] f32
    const int*   kapa = (const int*)d_in[4];    // [16384] int32
    // d_in[5] = batch_size (scalar), d_in[6] = features (dead) — unused
    const float* mean = (const float*)d_in[7];  // [4] f32
    float* out = (float*)d_out;                 // [16384] f32

    bayes_kernel<<<16384, 256, 0, stream>>>(A, Bo, BEVa, BEVb, kapa, mean, out);
}